// Round 5
// baseline (2173.614 us; speedup 1.0000x reference)
//
#include <hip/hip_runtime.h>

typedef __attribute__((ext_vector_type(8))) short bf16x8;
typedef __attribute__((ext_vector_type(4))) float f32x4;

#define T_ 1024

// round-to-nearest-even f32 -> bf16 bits (scalar)
__device__ __forceinline__ unsigned short f2bf(float f) {
  unsigned int u = __float_as_uint(f);
  u += 0x7fffu + ((u >> 16) & 1u);
  return (unsigned short)(u >> 16);
}

// pack 2 f32 -> 2 bf16 (RNE), one instruction
__device__ __forceinline__ unsigned int cvtpk(float a, float b) {
  unsigned int r;
  asm("v_cvt_pk_bf16_f32 %0, %1, %2" : "=v"(r) : "v"(a), "v"(b));
  return r;
}

// tanh(x) = 1 - 2*rcp(1 + exp2(x * 2/ln2)); saturates to +-1, no NaN for finite x
__device__ __forceinline__ float tanh_fast(float x) {
  float e = __builtin_amdgcn_exp2f(x * 2.8853900817779268f);
  return __builtin_fmaf(-2.0f, __builtin_amdgcn_rcpf(1.0f + e), 1.0f);
}

// ---- 4 weight matrices [256][256] f32 -> transposed bf16 [u][f], packed at d + w*65536 ----
__global__ __launch_bounds__(256) void k_cvt_w(const float* __restrict__ s0,
                                               const float* __restrict__ s1,
                                               const float* __restrict__ s2,
                                               const float* __restrict__ s3,
                                               unsigned short* __restrict__ d) {
  int w = blockIdx.x >> 8, f = blockIdx.x & 255, u = threadIdx.x;
  const float* s = w == 0 ? s0 : w == 1 ? s1 : w == 2 ? s2 : s3;
  d[w * 65536 + u * 256 + f] = f2bf(s[f * 256 + u]);
}

// ---- C[M x 256] = A(f32 [M x 256], converted inline) @ W + bias, swapped operands ----
// WG = 256 thr (4 waves); block owns 16 A-rows; wave owns n in [64w, 64w+64).
__global__ __launch_bounds__(256) void k_gemm(const float* __restrict__ A,
                                              const unsigned short* __restrict__ WT,
                                              const float* __restrict__ bias,
                                              float* __restrict__ C) {
  const int wave = threadIdx.x >> 6, lane = threadIdx.x & 63;
  const int lo = lane & 15, hi = lane >> 4;
  const int n0 = wave * 64;
  const size_t mt = blockIdx.x;

  bf16x8 a[4][8];
#pragma unroll
  for (int nt = 0; nt < 4; ++nt)
#pragma unroll
    for (int kt = 0; kt < 8; ++kt)
      a[nt][kt] = *(const bf16x8*)(WT + (size_t)(n0 + nt * 16 + lo) * 256 + kt * 32 + hi * 8);

  const float* Ap = A + (mt * 16 + lo) * 256 + hi * 8;
  bf16x8 b[8];
#pragma unroll
  for (int kt = 0; kt < 8; ++kt) {
    float4 u = *(const float4*)(Ap + kt * 32);
    float4 v = *(const float4*)(Ap + kt * 32 + 4);
    union { bf16x8 v8; unsigned int w[4]; } r;
    r.w[0] = cvtpk(u.x, u.y); r.w[1] = cvtpk(u.z, u.w);
    r.w[2] = cvtpk(v.x, v.y); r.w[3] = cvtpk(v.z, v.w);
    b[kt] = r.v8;
  }

#pragma unroll
  for (int nt = 0; nt < 4; ++nt) {
    f32x4 acc = *(const f32x4*)(bias + n0 + nt * 16 + hi * 4);
#pragma unroll
    for (int kt = 0; kt < 8; ++kt)
      acc = __builtin_amdgcn_mfma_f32_16x16x32_bf16(a[nt][kt], b[kt], acc, 0, 0, 0);
    *(f32x4*)(C + (size_t)(mt * 16 + lo) * 256 + n0 + nt * 16 + hi * 4) = acc;
  }
}

// ---- fused producer-consumer scans: blocks 0-7 = encoder, 8-15 = decoder ----
// Each WG: 512 thr (8 waves, 2/SIMD -- r3's proven best structure); owns 16 batch rows;
// wave owns n in [32w, 32w+32). Weights VGPR-resident. h tile [16][256] bf16 in LDS,
// double-buffered, XOR-swizzled. One raw lgkm-only barrier per step.
// Encoder: h_t = tanh(xpe_t + h@WheT); streams h_t bf16 to hseq; every 16 steps
//   drains vmem and release-stores flags[g] = t+1 (agent scope, cross-XCD safe).
// Decoder: acquire-polls flags[g]; loads hseq[t] into B-frag regs (distance-1);
//   acc = dec_b -> 8 proj MFMA (hseq_t @ WpT) -> 8 rec MFMA (h@WhdT) -> tanh.
//   (xp_dec never materialized.) Final tanh (f32) -> out at t = T-1.
// Co-residency: 16 WGs, 1 WG/CU (launch_bounds 512,2), 16 of 256 CUs.
__global__ __launch_bounds__(512, 2) void k_scan2(const float* __restrict__ xpe,
                                                  const unsigned short* __restrict__ WheT,
                                                  const unsigned short* __restrict__ WhdT,
                                                  const unsigned short* __restrict__ WpT,
                                                  const float* __restrict__ pbias,
                                                  unsigned short* __restrict__ hseq,
                                                  float* __restrict__ out,
                                                  unsigned int* __restrict__ flags) {
  __shared__ __align__(16) char hb[16384];  // [2][16 b][256 k] bf16
  const int tid = threadIdx.x, wave = tid >> 6, lane = tid & 63;
  const int lo = lane & 15, hi = lane >> 4;
  const bool enc = blockIdx.x < 8;
  const int g = enc ? blockIdx.x : blockIdx.x - 8;
  const int n0 = wave * 32;

  // LDS byte addrs (step-invariant), XOR swizzle bits 4-6
  const int swz = (lo & 7) << 4;
  int raddr[8];
#pragma unroll
  for (int kt = 0; kt < 8; ++kt) raddr[kt] = (lo * 512 + kt * 64 + hi * 16) ^ swz;
  int waddr[2];
#pragma unroll
  for (int nt = 0; nt < 2; ++nt)
    waddr[nt] = (lo * 512 + (n0 + nt * 16 + hi * 4) * 2) ^ swz;

  // zero both h buffers (t=0 reads zeros = h0)
  for (int i = tid; i < 4096; i += 512) ((unsigned int*)hb)[i] = 0;
  __syncthreads();

  const size_t brow = (size_t)(g * 16 + lo);

  if (enc) {
    // ---------------- encoder ----------------
    bf16x8 ah[2][8];
#pragma unroll
    for (int nt = 0; nt < 2; ++nt)
#pragma unroll
      for (int kt = 0; kt < 8; ++kt)
        ah[nt][kt] = *(const bf16x8*)(WheT + (size_t)(n0 + nt * 16 + lo) * 256 + kt * 32 + hi * 8);

    const float* xpw = xpe + brow * T_ * 256 + n0 + hi * 4;
    unsigned short* hsp = hseq + brow * T_ * 256 + n0 + hi * 4;

    f32x4 xva[2], xvb[2];
#pragma unroll
    for (int nt = 0; nt < 2; ++nt) {
      xva[nt] = *(const f32x4*)(xpw + nt * 16);
      xvb[nt] = *(const f32x4*)(xpw + 256 + nt * 16);
    }

    auto estep = [&](int t, f32x4 (&xv)[2], int ro, int wo) {
      bf16x8 b[8];
#pragma unroll
      for (int kt = 0; kt < 8; ++kt) b[kt] = *(const bf16x8*)(hb + ro + raddr[kt]);
      f32x4 c0 = xv[0], c1 = xv[1];
#pragma unroll
      for (int kt = 0; kt < 8; ++kt) {
        c0 = __builtin_amdgcn_mfma_f32_16x16x32_bf16(ah[0][kt], b[kt], c0, 0, 0, 0);
        c1 = __builtin_amdgcn_mfma_f32_16x16x32_bf16(ah[1][kt], b[kt], c1, 0, 0, 0);
      }
      {  // refill this parity for t+2
        const int tn = (t + 2 <= T_ - 1) ? t + 2 : T_ - 1;
#pragma unroll
        for (int nt = 0; nt < 2; ++nt)
          xv[nt] = *(const f32x4*)(xpw + (size_t)tn * 256 + nt * 16);
      }
      float th[8];
#pragma unroll
      for (int q = 0; q < 8; ++q) th[q] = tanh_fast(q < 4 ? c0[q] : c1[q - 4]);
      unsigned int pk[4];
      pk[0] = cvtpk(th[0], th[1]); pk[1] = cvtpk(th[2], th[3]);
      pk[2] = cvtpk(th[4], th[5]); pk[3] = cvtpk(th[6], th[7]);
      // stream h_t to hseq (in flight across steps)
      {
        uint2 w0 = {pk[0], pk[1]}, w1 = {pk[2], pk[3]};
        *(uint2*)(hsp + (size_t)t * 256) = w0;
        *(uint2*)(hsp + (size_t)t * 256 + 16) = w1;
      }
      // write h_t to the other LDS buffer
      {
        uint2 w0 = {pk[0], pk[1]}, w1 = {pk[2], pk[3]};
        *(uint2*)(hb + wo + waddr[0]) = w0;
        *(uint2*)(hb + wo + waddr[1]) = w1;
      }
      if ((t & 15) == 15) {
        // drain all vmem (hseq stores incl.), sync WG, then publish progress
        asm volatile("s_waitcnt vmcnt(0) lgkmcnt(0)\n\ts_barrier" ::: "memory");
        if (tid == 0)
          __hip_atomic_store(&flags[g], (unsigned int)(t + 1), __ATOMIC_RELEASE,
                             __HIP_MEMORY_SCOPE_AGENT);
      } else {
        asm volatile("s_waitcnt lgkmcnt(0)\n\ts_barrier" ::: "memory");
      }
    };

    for (int t = 0; t < T_; t += 2) {
      estep(t, xva, 8192, 0);
      estep(t + 1, xvb, 0, 8192);
    }
  } else {
    // ---------------- decoder ----------------
    bf16x8 ah[2][8], ap[2][8];
#pragma unroll
    for (int nt = 0; nt < 2; ++nt)
#pragma unroll
      for (int kt = 0; kt < 8; ++kt) {
        const size_t n = n0 + nt * 16 + lo;
        ah[nt][kt] = *(const bf16x8*)(WhdT + n * 256 + kt * 32 + hi * 8);
        ap[nt][kt] = *(const bf16x8*)(WpT + n * 256 + kt * 32 + hi * 8);
      }
    f32x4 pbv[2];
#pragma unroll
    for (int nt = 0; nt < 2; ++nt) pbv[nt] = *(const f32x4*)(pbias + n0 + nt * 16 + hi * 4);

    // B-frag source for proj: thread reads hseq[b=lo][t][kt*32 + hi*8 ..+8]
    const unsigned short* hqp = hseq + brow * T_ * 256 + hi * 8;
    unsigned int known = 0;
    auto waitflag = [&](unsigned int need) {
      while (known < need)
        known = __hip_atomic_load(&flags[g], __ATOMIC_ACQUIRE, __HIP_MEMORY_SCOPE_AGENT);
    };

    bf16x8 hq[8];
    waitflag(1);
#pragma unroll
    for (int kt = 0; kt < 8; ++kt) hq[kt] = *(const bf16x8*)(hqp + kt * 32);

    auto dstep = [&](int t, int ro, int wo) {
      bf16x8 b[8];
#pragma unroll
      for (int kt = 0; kt < 8; ++kt) b[kt] = *(const bf16x8*)(hb + ro + raddr[kt]);
      // xp_dec on the fly: acc = dec_b + hseq_t @ WpT ...
      f32x4 c0 = pbv[0], c1 = pbv[1];
#pragma unroll
      for (int kt = 0; kt < 8; ++kt) {
        c0 = __builtin_amdgcn_mfma_f32_16x16x32_bf16(ap[0][kt], hq[kt], c0, 0, 0, 0);
        c1 = __builtin_amdgcn_mfma_f32_16x16x32_bf16(ap[1][kt], hq[kt], c1, 0, 0, 0);
      }
      // hq now dead: refill for t+1 (distance-1; ~a full step of latency hiding)
      if (t < T_ - 1) {
        waitflag((unsigned int)(t + 2));
        const unsigned short* p = hqp + (size_t)(t + 1) * 256;
#pragma unroll
        for (int kt = 0; kt < 8; ++kt) hq[kt] = *(const bf16x8*)(p + kt * 32);
      }
      // ... + h_{t-1} @ WhdT
#pragma unroll
      for (int kt = 0; kt < 8; ++kt) {
        c0 = __builtin_amdgcn_mfma_f32_16x16x32_bf16(ah[0][kt], b[kt], c0, 0, 0, 0);
        c1 = __builtin_amdgcn_mfma_f32_16x16x32_bf16(ah[1][kt], b[kt], c1, 0, 0, 0);
      }
      float th[8];
#pragma unroll
      for (int q = 0; q < 8; ++q) th[q] = tanh_fast(q < 4 ? c0[q] : c1[q - 4]);
      if (t == T_ - 1) {  // final hidden state, f32 [128][256]
        float* op = out + brow * 256 + n0 + hi * 4;
        f32x4 o0 = {th[0], th[1], th[2], th[3]};
        f32x4 o1 = {th[4], th[5], th[6], th[7]};
        *(f32x4*)(op) = o0;
        *(f32x4*)(op + 16) = o1;
      }
      {
        uint2 w0 = {cvtpk(th[0], th[1]), cvtpk(th[2], th[3])};
        uint2 w1 = {cvtpk(th[4], th[5]), cvtpk(th[6], th[7])};
        *(uint2*)(hb + wo + waddr[0]) = w0;
        *(uint2*)(hb + wo + waddr[1]) = w1;
      }
      asm volatile("s_waitcnt lgkmcnt(0)\n\ts_barrier" ::: "memory");
    };

    for (int t = 0; t < T_; t += 2) {
      dstep(t, 8192, 0);
      dstep(t + 1, 0, 8192);
    }
  }
}

extern "C" void kernel_launch(void* const* d_in, const int* in_sizes, int n_in,
                              void* d_out, int out_size, void* d_ws, size_t ws_size,
                              hipStream_t stream) {
  const float* x      = (const float*)d_in[0];
  const float* enc_Wx = (const float*)d_in[1];
  const float* enc_Wh = (const float*)d_in[2];
  const float* enc_b  = (const float*)d_in[3];
  const float* dec_Wx = (const float*)d_in[4];
  const float* dec_Wh = (const float*)d_in[5];
  const float* dec_b  = (const float*)d_in[6];

  char* ws = (char*)d_ws;
  float*          xpe   = (float*)ws;                                  // 128MB xp_enc
  unsigned short* hseq  = (unsigned short*)(ws + ((size_t)128 << 20)); // 64MB bf16 h_seq
  unsigned short* wT    = (unsigned short*)(ws + ((size_t)192 << 20)); // 4 x 128KB bf16 W^T
  unsigned int*   flags = (unsigned int*)(ws + ((size_t)193 << 20));   // 8 x u32 progress

  // flags must be zero at every call (ws is poisoned once, never re-poisoned)
  hipMemsetAsync(flags, 0, 64, stream);
  // wT layout: [0]=enc_Wx^T  [1]=enc_Wh^T  [2]=dec_Wx^T  [3]=dec_Wh^T
  k_cvt_w<<<1024, 256, 0, stream>>>(enc_Wx, enc_Wh, dec_Wx, dec_Wh, wT);
  // xp_enc = x @ enc_Wx + enc_b
  k_gemm<<<8192, 256, 0, stream>>>(x, wT, enc_b, xpe);
  // overlapped encoder (blocks 0-7) + decoder (blocks 8-15)
  k_scan2<<<16, 512, 0, stream>>>(xpe, wT + 65536, wT + 196608, wT + 131072,
                                  dec_b, hseq, (float*)d_out, flags);
}